// Round 10
// baseline (118.394 us; speedup 1.0000x reference)
//
#include <hip/hip_runtime.h>

typedef __attribute__((ext_vector_type(8))) short short8v;
typedef __attribute__((ext_vector_type(4))) float f32x4;
typedef __attribute__((ext_vector_type(4))) int i32x4;

#define BATCH 128
#define CIN 8
#define HW 128
#define COUT 64
#define OHW 126
#define NG 16
#define PH 31
#define GN_EPS 1e-5f

#define ROWS_A 8
#define STRIPS_A 16
#define INROWS_A 11   // 10 real + 1 zero pad (for g=3 reads)
#define ACOLS 132

static __device__ __forceinline__ unsigned short f2bf(float f) {
    unsigned u = __float_as_uint(f);
    return (unsigned short)((u + 0x7fffu + ((u >> 16) & 1u)) >> 16);
}
static __device__ __forceinline__ unsigned pk2(float a, float b) {
    return (unsigned)f2bf(a) | ((unsigned)f2bf(b) << 16);
}

// ---- prep: pack weights * sgn_c into MFMA B-fragment order, bf16 ----
// (sgn = sign(gnw*scale); multiply by ±1 is exact, conv magnitudes unchanged)
__global__ __launch_bounds__(256) void prep_weights(
    const float* __restrict__ w, const float* __restrict__ gnw,
    const float* __restrict__ scale, short* __restrict__ Bpack)
{
    for (int e = threadIdx.x; e < 3 * 4 * 64; e += 256) {
        int dx = e >> 8;
        int nt = (e >> 6) & 3;
        int l  = e & 63;
        int i = l & 15, g = l >> 4;
        int n = nt * 16 + i;
        float sg = copysignf(1.f, gnw[n] * scale[n]);
        #pragma unroll
        for (int j = 0; j < 8; ++j) {
            float v = (g < 3) ? w[((n * CIN + j) * 3 + g) * 3 + dx] * sg : 0.f;
            Bpack[e * 8 + j] = (short)f2bf(v);
        }
    }
}

// ---- pass A: bf16-MFMA conv ONCE (weights sgn-folded).
//      Hot-loop epilogue = 3 ops/elem: s1+=a, s2=fma(a,a), mz=fmax.
//      Staging / ds-reads / MFMA / reduce byte-identical to round-9 proven. ----
__global__ __launch_bounds__(256, 6) void conv_fused(
    const float* __restrict__ x, const short* __restrict__ Bpack,
    const float* __restrict__ bias, const float* __restrict__ gnw,
    const float* __restrict__ scale, float* __restrict__ part,
    float* __restrict__ mzbuf)
{
    __shared__ __align__(16) short Abuf[INROWS_A][ACOLS][8];
    __shared__ float red[4][NG][2];
    const int strip = blockIdx.x, b = blockIdx.y;
    const int tid = threadIdx.x, wave = tid >> 6, lane = tid & 63;
    const int i = lane & 15, g = lane >> 4;
    const int r0 = strip * ROWS_A;

    // B fragments into registers (12 x 16B)
    short8v bq[3][4];
    {
        const i32x4* bp = (const i32x4*)Bpack;
        #pragma unroll
        for (int dx = 0; dx < 3; ++dx)
            #pragma unroll
            for (int nt = 0; nt < 4; ++nt) {
                i32x4 v = bp[(dx * 4 + nt) * 64 + lane];
                bq[dx][nt] = *(short8v*)&v;
            }
    }
    float sgn[4], bs2[4], bsg[4];   // post-loop / store-time only
    #pragma unroll
    for (int nt = 0; nt < 4; ++nt) {
        int c = nt * 16 + i;
        float bc = bias[c];
        float sg = copysignf(1.f, gnw[c] * scale[c]);
        sgn[nt] = sg;
        bs2[nt] = 2.f * bc;
        bsg[nt] = sg * bc;
    }

    // staging — round-2 verbatim
    {
        const float* xb = x + (size_t)b * CIN * HW * HW;
        for (int e = tid; e < INROWS_A * ACOLS; e += 256) {
            int row = e / ACOLS, col = e % ACOLS;
            int ri = r0 + row;
            bool ok = (row < 10) && (ri < HW) && (col < HW);
            unsigned pk0, pk1, pk2_, pk3;
            {
                const float* base = &xb[(size_t)ri * HW + col];
                float v0 = ok ? base[0 * HW * HW] : 0.f;
                float v1 = ok ? base[1 * HW * HW] : 0.f;
                float v2 = ok ? base[2 * HW * HW] : 0.f;
                float v3 = ok ? base[3 * HW * HW] : 0.f;
                float v4 = ok ? base[4 * HW * HW] : 0.f;
                float v5 = ok ? base[5 * HW * HW] : 0.f;
                float v6 = ok ? base[6 * HW * HW] : 0.f;
                float v7 = ok ? base[7 * HW * HW] : 0.f;
                pk0  = pk2(v0, v1);
                pk1  = pk2(v2, v3);
                pk2_ = pk2(v4, v5);
                pk3  = pk2(v6, v7);
            }
            uint4 w4 = make_uint4(pk0, pk1, pk2_, pk3);
            *(uint4*)&Abuf[row][col][0] = w4;
        }
    }
    __syncthreads();

    float s1[4] = {0.f, 0.f, 0.f, 0.f}, s2[4] = {0.f, 0.f, 0.f, 0.f};
    const int myprow = wave & 1;        // pool row within strip
    const int tbase  = (wave >> 1) * 4; // t-half
    const int prow_g = strip * 2 + myprow;

    for (int tl = 0; tl < 4; ++tl) {
        const int t = tbase + tl;
        float mz[4] = {-3e38f, -3e38f, -3e38f, -3e38f};
        #pragma unroll
        for (int ri_ = 0; ri_ < 4; ++ri_) {
            const int rloc = 4 * myprow + ri_;
            if (r0 + rloc < OHW) {
                f32x4 acc[4];
                #pragma unroll
                for (int nt = 0; nt < 4; ++nt) acc[nt] = (f32x4){0.f, 0.f, 0.f, 0.f};
                #pragma unroll
                for (int dx = 0; dx < 3; ++dx) {
                    short8v a = *(const short8v*)&Abuf[rloc + g][16 * t + i + dx][0];
                    #pragma unroll
                    for (int nt = 0; nt < 4; ++nt)
                        acc[nt] = __builtin_amdgcn_mfma_f32_16x16x32_bf16(a, bq[dx][nt], acc[nt], 0, 0, 0);
                }
                const int nv = (t == 7 && g == 3) ? 2 : 4;  // cols >=126 excluded from stats
                #pragma unroll
                for (int nt = 0; nt < 4; ++nt) {
                    #pragma unroll
                    for (int r = 0; r < 4; ++r)
                        if (r < nv) {
                            float a = acc[nt][r];
                            s1[nt] += a;
                            s2[nt] = fmaf(a, a, s2[nt]);
                        }
                    // window max of acc' = sgn*conv_raw; invalid cols only feed pc=31 (never stored)
                    mz[nt] = fmaxf(mz[nt],
                             fmaxf(fmaxf(acc[nt][0], acc[nt][1]),
                                   fmaxf(acc[nt][2], acc[nt][3])));
                }
            }
        }
        const int pc = 4 * t + g;
        if (prow_g < PH && pc < PH) {
            float* dst = &mzbuf[((size_t)(b * PH + prow_g) * 32 + pc) * 64 + i];
            #pragma unroll
            for (int nt = 0; nt < 4; ++nt) dst[nt * 16] = mz[nt] + bsg[nt];  // = max(sgn*(raw+bias))
        }
    }

    // post-loop bias/sign fixup (linear in partials), then round-2 reduce
    #pragma unroll
    for (int nt = 0; nt < 4; ++nt) {
        float t1 = s1[nt] * sgn[nt];            // sum of conv_raw
        s2[nt] = fmaf(bs2[nt], t1, s2[nt]);     // + 2*b*sum(raw); squares sign-invariant
        s1[nt] = t1;
    }
    #pragma unroll
    for (int nt = 0; nt < 4; ++nt) {
        s1[nt] += __shfl_xor(s1[nt], 1);  s1[nt] += __shfl_xor(s1[nt], 2);
        s1[nt] += __shfl_xor(s1[nt], 16); s1[nt] += __shfl_xor(s1[nt], 32);
        s2[nt] += __shfl_xor(s2[nt], 1);  s2[nt] += __shfl_xor(s2[nt], 2);
        s2[nt] += __shfl_xor(s2[nt], 16); s2[nt] += __shfl_xor(s2[nt], 32);
    }
    if (g == 0 && (i & 3) == 0) {
        #pragma unroll
        for (int nt = 0; nt < 4; ++nt) {
            red[wave][nt * 4 + (i >> 2)][0] = s1[nt];
            red[wave][nt * 4 + (i >> 2)][1] = s2[nt];
        }
    }
    __syncthreads();
    if (tid < 32) {
        int grp = tid >> 1, which = tid & 1;
        float v = red[0][grp][which] + red[1][grp][which] + red[2][grp][which] + red[3][grp][which];
        part[(((size_t)b * STRIPS_A + strip) * NG + grp) * 2 + which] = v;
    }
}

// ---- merged: per-b stats finalize (+ bias N-terms) + affine + clamp + transpose-write ----
__global__ __launch_bounds__(256) void finalize_affine(
    const float* __restrict__ part, const float* __restrict__ gnw,
    const float* __restrict__ gnb, const float* __restrict__ scale,
    const float* __restrict__ bias, const float* __restrict__ mzbuf,
    float* __restrict__ out)
{
    __shared__ float sl[PH * 65];   // [pw][c], stride 65 (bank-spread)
    __shared__ float A2s[COUT], Bvs[COUT];
    const int ph = blockIdx.x, b = blockIdx.y;
    const int tid = threadIdx.x;

    if (tid < COUT) {
        const int c = tid, grp = c >> 2;
        float s1 = 0.f, s2 = 0.f;
        for (int s = 0; s < STRIPS_A; ++s) {
            const float* p = &part[(((size_t)b * STRIPS_A + s) * NG + grp) * 2];
            s1 += p[0]; s2 += p[1];
        }
        // add N*sum(b) and N*sum(b^2) group terms (bias fully out of conv kernel)
        float sumb = 0.f, sumb2 = 0.f;
        #pragma unroll
        for (int ci = 0; ci < 4; ++ci) {
            float bc = bias[grp * 4 + ci];
            sumb += bc; sumb2 += bc * bc;
        }
        const float N1 = (float)(OHW * OHW);
        float S1 = s1 + N1 * sumb;
        float S2 = s2 + N1 * sumb2;
        const float invN = 1.f / (4.f * N1);
        float mean = S1 * invN;
        float var  = S2 * invN - mean * mean;
        float rstd = rsqrtf(var + GN_EPS);
        float gs = gnw[c] * scale[c];
        A2s[c] = rstd * fabsf(gs);   // >= 0
        Bvs[c] = (gnb[c] - mean * rstd * gnw[c]) * scale[c];
    }

    const float* src = mzbuf + (size_t)(b * PH + ph) * 32 * 64;
    for (int e = tid; e < PH * 64; e += 256) {
        int pc = e >> 6, c = e & 63;
        sl[pc * 65 + c] = src[pc * 64 + c];
    }
    __syncthreads();

    const int c = tid >> 2, q = tid & 3;
    const float A2 = A2s[c];
    const float B0 = Bvs[c];
    float* ob = out + (size_t)(b * COUT + c) * (PH * PH) + ph * PH;
    #pragma unroll
    for (int k = 0; k < 8; ++k) {
        int pw = q * 8 + k;
        if (pw < PH) {
            float v = fmaf(A2, sl[pw * 65 + c], B0);
            ob[pw] = fminf(fmaxf(v, 0.f), 1.f);
        }
    }
}

extern "C" void kernel_launch(void* const* d_in, const int* in_sizes, int n_in,
                              void* d_out, int out_size, void* d_ws, size_t ws_size,
                              hipStream_t stream)
{
    const float* x   = (const float*)d_in[0];
    const float* w   = (const float*)d_in[1];
    const float* cbv = (const float*)d_in[2];
    const float* gnw = (const float*)d_in[3];
    const float* gnb = (const float*)d_in[4];
    const float* sc  = (const float*)d_in[5];
    float* out = (float*)d_out;

    float* mzbuf = (float*)d_ws;                          // 128*31*32*64 f32 = 32.5 MB
    float* part  = mzbuf + (size_t)BATCH * PH * 32 * 64;  // 65536 f32
    short* Bpack = (short*)(part + 65536);                // 6144 bf16

    prep_weights<<<dim3(1), 256, 0, stream>>>(w, gnw, sc, Bpack);
    conv_fused<<<dim3(STRIPS_A, BATCH), 256, 0, stream>>>(x, Bpack, cbv, gnw, sc, part, mzbuf);
    finalize_affine<<<dim3(PH, BATCH), 256, 0, stream>>>(part, gnw, gnb, sc, cbv, mzbuf, out);
}

// Round 11
// 66.579 us; speedup vs baseline: 1.7783x; 1.7783x over previous
//
#include <hip/hip_runtime.h>

typedef __attribute__((ext_vector_type(8))) short short8v;
typedef __attribute__((ext_vector_type(4))) float f32x4;
typedef __attribute__((ext_vector_type(4))) int i32x4;

#define BATCH 128
#define CIN 8
#define HW 128
#define COUT 64
#define OHW 126
#define NG 16
#define PH 31
#define GN_EPS 1e-5f

#define ROWS_A 8
#define STRIPS_A 16
#define INROWS_A 11   // 10 real + 1 zero pad (for g=3 reads)
#define ACOLS 132

static __device__ __forceinline__ unsigned short f2bf(float f) {
    unsigned u = __float_as_uint(f);
    return (unsigned short)((u + 0x7fffu + ((u >> 16) & 1u)) >> 16);
}
static __device__ __forceinline__ unsigned pk2(float a, float b) {
    return (unsigned)f2bf(a) | ((unsigned)f2bf(b) << 16);
}

// ---- prep: pack weights * sgn_c into MFMA B-fragment order, bf16 ----
__global__ __launch_bounds__(256) void prep_weights(
    const float* __restrict__ w, const float* __restrict__ gnw,
    const float* __restrict__ scale, short* __restrict__ Bpack)
{
    for (int e = threadIdx.x; e < 3 * 4 * 64; e += 256) {
        int dx = e >> 8;
        int nt = (e >> 6) & 3;
        int l  = e & 63;
        int i = l & 15, g = l >> 4;
        int n = nt * 16 + i;
        float sg = copysignf(1.f, gnw[n] * scale[n]);
        #pragma unroll
        for (int j = 0; j < 8; ++j) {
            float v = (g < 3) ? w[((n * CIN + j) * 3 + g) * 3 + dx] * sg : 0.f;
            Bpack[e * 8 + j] = (short)f2bf(v);
        }
    }
}

// ---- pass A: bf16-MFMA conv ONCE (weights sgn-folded).
//      Hot-loop epilogue = 3 ops/elem. ONLY change vs round-10: launch_bounds 6->4. ----
__global__ __launch_bounds__(256, 4) void conv_fused(
    const float* __restrict__ x, const short* __restrict__ Bpack,
    const float* __restrict__ bias, const float* __restrict__ gnw,
    const float* __restrict__ scale, float* __restrict__ part,
    float* __restrict__ mzbuf)
{
    __shared__ __align__(16) short Abuf[INROWS_A][ACOLS][8];
    __shared__ float red[4][NG][2];
    const int strip = blockIdx.x, b = blockIdx.y;
    const int tid = threadIdx.x, wave = tid >> 6, lane = tid & 63;
    const int i = lane & 15, g = lane >> 4;
    const int r0 = strip * ROWS_A;

    // B fragments into registers (12 x 16B)
    short8v bq[3][4];
    {
        const i32x4* bp = (const i32x4*)Bpack;
        #pragma unroll
        for (int dx = 0; dx < 3; ++dx)
            #pragma unroll
            for (int nt = 0; nt < 4; ++nt) {
                i32x4 v = bp[(dx * 4 + nt) * 64 + lane];
                bq[dx][nt] = *(short8v*)&v;
            }
    }
    float sgn[4], bs2[4], bsg[4];   // post-loop / store-time only
    #pragma unroll
    for (int nt = 0; nt < 4; ++nt) {
        int c = nt * 16 + i;
        float bc = bias[c];
        float sg = copysignf(1.f, gnw[c] * scale[c]);
        sgn[nt] = sg;
        bs2[nt] = 2.f * bc;
        bsg[nt] = sg * bc;
    }

    // staging — round-2 verbatim
    {
        const float* xb = x + (size_t)b * CIN * HW * HW;
        for (int e = tid; e < INROWS_A * ACOLS; e += 256) {
            int row = e / ACOLS, col = e % ACOLS;
            int ri = r0 + row;
            bool ok = (row < 10) && (ri < HW) && (col < HW);
            unsigned pk0, pk1, pk2_, pk3;
            {
                const float* base = &xb[(size_t)ri * HW + col];
                float v0 = ok ? base[0 * HW * HW] : 0.f;
                float v1 = ok ? base[1 * HW * HW] : 0.f;
                float v2 = ok ? base[2 * HW * HW] : 0.f;
                float v3 = ok ? base[3 * HW * HW] : 0.f;
                float v4 = ok ? base[4 * HW * HW] : 0.f;
                float v5 = ok ? base[5 * HW * HW] : 0.f;
                float v6 = ok ? base[6 * HW * HW] : 0.f;
                float v7 = ok ? base[7 * HW * HW] : 0.f;
                pk0  = pk2(v0, v1);
                pk1  = pk2(v2, v3);
                pk2_ = pk2(v4, v5);
                pk3  = pk2(v6, v7);
            }
            uint4 w4 = make_uint4(pk0, pk1, pk2_, pk3);
            *(uint4*)&Abuf[row][col][0] = w4;
        }
    }
    __syncthreads();

    float s1[4] = {0.f, 0.f, 0.f, 0.f}, s2[4] = {0.f, 0.f, 0.f, 0.f};
    const int myprow = wave & 1;        // pool row within strip
    const int tbase  = (wave >> 1) * 4; // t-half
    const int prow_g = strip * 2 + myprow;

    for (int tl = 0; tl < 4; ++tl) {
        const int t = tbase + tl;
        float mz[4] = {-3e38f, -3e38f, -3e38f, -3e38f};
        #pragma unroll
        for (int ri_ = 0; ri_ < 4; ++ri_) {
            const int rloc = 4 * myprow + ri_;
            if (r0 + rloc < OHW) {
                f32x4 acc[4];
                #pragma unroll
                for (int nt = 0; nt < 4; ++nt) acc[nt] = (f32x4){0.f, 0.f, 0.f, 0.f};
                #pragma unroll
                for (int dx = 0; dx < 3; ++dx) {
                    short8v a = *(const short8v*)&Abuf[rloc + g][16 * t + i + dx][0];
                    #pragma unroll
                    for (int nt = 0; nt < 4; ++nt)
                        acc[nt] = __builtin_amdgcn_mfma_f32_16x16x32_bf16(a, bq[dx][nt], acc[nt], 0, 0, 0);
                }
                const int nv = (t == 7 && g == 3) ? 2 : 4;  // cols >=126 excluded from stats
                #pragma unroll
                for (int nt = 0; nt < 4; ++nt) {
                    #pragma unroll
                    for (int r = 0; r < 4; ++r)
                        if (r < nv) {
                            float a = acc[nt][r];
                            s1[nt] += a;
                            s2[nt] = fmaf(a, a, s2[nt]);
                        }
                    // window max of acc' = sgn*conv_raw; invalid cols only feed pc=31 (never stored)
                    mz[nt] = fmaxf(mz[nt],
                             fmaxf(fmaxf(acc[nt][0], acc[nt][1]),
                                   fmaxf(acc[nt][2], acc[nt][3])));
                }
            }
        }
        const int pc = 4 * t + g;
        if (prow_g < PH && pc < PH) {
            float* dst = &mzbuf[((size_t)(b * PH + prow_g) * 32 + pc) * 64 + i];
            #pragma unroll
            for (int nt = 0; nt < 4; ++nt) dst[nt * 16] = mz[nt] + bsg[nt];  // = max(sgn*(raw+bias))
        }
    }

    // post-loop bias/sign fixup (linear in partials), then round-2 reduce
    #pragma unroll
    for (int nt = 0; nt < 4; ++nt) {
        float t1 = s1[nt] * sgn[nt];            // sum of conv_raw
        s2[nt] = fmaf(bs2[nt], t1, s2[nt]);     // + 2*b*sum(raw); squares sign-invariant
        s1[nt] = t1;
    }
    #pragma unroll
    for (int nt = 0; nt < 4; ++nt) {
        s1[nt] += __shfl_xor(s1[nt], 1);  s1[nt] += __shfl_xor(s1[nt], 2);
        s1[nt] += __shfl_xor(s1[nt], 16); s1[nt] += __shfl_xor(s1[nt], 32);
        s2[nt] += __shfl_xor(s2[nt], 1);  s2[nt] += __shfl_xor(s2[nt], 2);
        s2[nt] += __shfl_xor(s2[nt], 16); s2[nt] += __shfl_xor(s2[nt], 32);
    }
    if (g == 0 && (i & 3) == 0) {
        #pragma unroll
        for (int nt = 0; nt < 4; ++nt) {
            red[wave][nt * 4 + (i >> 2)][0] = s1[nt];
            red[wave][nt * 4 + (i >> 2)][1] = s2[nt];
        }
    }
    __syncthreads();
    if (tid < 32) {
        int grp = tid >> 1, which = tid & 1;
        float v = red[0][grp][which] + red[1][grp][which] + red[2][grp][which] + red[3][grp][which];
        part[(((size_t)b * STRIPS_A + strip) * NG + grp) * 2 + which] = v;
    }
}

// ---- merged: per-b stats finalize (+ bias N-terms) + affine + clamp + transpose-write ----
__global__ __launch_bounds__(256) void finalize_affine(
    const float* __restrict__ part, const float* __restrict__ gnw,
    const float* __restrict__ gnb, const float* __restrict__ scale,
    const float* __restrict__ bias, const float* __restrict__ mzbuf,
    float* __restrict__ out)
{
    __shared__ float sl[PH * 65];   // [pw][c], stride 65 (bank-spread)
    __shared__ float A2s[COUT], Bvs[COUT];
    const int ph = blockIdx.x, b = blockIdx.y;
    const int tid = threadIdx.x;

    if (tid < COUT) {
        const int c = tid, grp = c >> 2;
        float s1 = 0.f, s2 = 0.f;
        for (int s = 0; s < STRIPS_A; ++s) {
            const float* p = &part[(((size_t)b * STRIPS_A + s) * NG + grp) * 2];
            s1 += p[0]; s2 += p[1];
        }
        float sumb = 0.f, sumb2 = 0.f;
        #pragma unroll
        for (int ci = 0; ci < 4; ++ci) {
            float bc = bias[grp * 4 + ci];
            sumb += bc; sumb2 += bc * bc;
        }
        const float N1 = (float)(OHW * OHW);
        float S1 = s1 + N1 * sumb;
        float S2 = s2 + N1 * sumb2;
        const float invN = 1.f / (4.f * N1);
        float mean = S1 * invN;
        float var  = S2 * invN - mean * mean;
        float rstd = rsqrtf(var + GN_EPS);
        float gs = gnw[c] * scale[c];
        A2s[c] = rstd * fabsf(gs);   // >= 0
        Bvs[c] = (gnb[c] - mean * rstd * gnw[c]) * scale[c];
    }

    const float* src = mzbuf + (size_t)(b * PH + ph) * 32 * 64;
    for (int e = tid; e < PH * 64; e += 256) {
        int pc = e >> 6, c = e & 63;
        sl[pc * 65 + c] = src[pc * 64 + c];
    }
    __syncthreads();

    const int c = tid >> 2, q = tid & 3;
    const float A2 = A2s[c];
    const float B0 = Bvs[c];
    float* ob = out + (size_t)(b * COUT + c) * (PH * PH) + ph * PH;
    #pragma unroll
    for (int k = 0; k < 8; ++k) {
        int pw = q * 8 + k;
        if (pw < PH) {
            float v = fmaf(A2, sl[pw * 65 + c], B0);
            ob[pw] = fminf(fmaxf(v, 0.f), 1.f);
        }
    }
}

extern "C" void kernel_launch(void* const* d_in, const int* in_sizes, int n_in,
                              void* d_out, int out_size, void* d_ws, size_t ws_size,
                              hipStream_t stream)
{
    const float* x   = (const float*)d_in[0];
    const float* w   = (const float*)d_in[1];
    const float* cbv = (const float*)d_in[2];
    const float* gnw = (const float*)d_in[3];
    const float* gnb = (const float*)d_in[4];
    const float* sc  = (const float*)d_in[5];
    float* out = (float*)d_out;

    float* mzbuf = (float*)d_ws;                          // 128*31*32*64 f32 = 32.5 MB
    float* part  = mzbuf + (size_t)BATCH * PH * 32 * 64;  // 65536 f32
    short* Bpack = (short*)(part + 65536);                // 6144 bf16

    prep_weights<<<dim3(1), 256, 0, stream>>>(w, gnw, sc, Bpack);
    conv_fused<<<dim3(STRIPS_A, BATCH), 256, 0, stream>>>(x, Bpack, cbv, gnw, sc, part, mzbuf);
    finalize_affine<<<dim3(PH, BATCH), 256, 0, stream>>>(part, gnw, gnb, sc, cbv, mzbuf, out);
}